// Round 6
// baseline (168.639 us; speedup 1.0000x reference)
//
#include <hip/hip_runtime.h>

typedef float f32x4 __attribute__((ext_vector_type(4)));
typedef __bf16 bf16x8 __attribute__((ext_vector_type(8)));

constexpr float INV_SQRT_F = 0.17677669529663687f;  // 32^-0.5

__device__ __forceinline__ f32x4 mfma16(bf16x8 a, bf16x8 b) {
  const f32x4 z = {0.f, 0.f, 0.f, 0.f};
  return __builtin_amdgcn_mfma_f32_16x16x32_bf16(a, b, z, 0, 0, 0);
}

__device__ __forceinline__ bf16x8 load_frag8(const float* __restrict__ p) {
  f32x4 u = *reinterpret_cast<const f32x4*>(p);
  f32x4 v = *reinterpret_cast<const f32x4*>(p + 4);
  bf16x8 r;
  r[0] = (__bf16)u[0]; r[1] = (__bf16)u[1]; r[2] = (__bf16)u[2]; r[3] = (__bf16)u[3];
  r[4] = (__bf16)v[0]; r[5] = (__bf16)v[1]; r[6] = (__bf16)v[2]; r[7] = (__bf16)v[3];
  return r;
}

// R6: wave-pair feature-half split (R4 layout, half the per-wave footprint).
// Waves (2t, 2t+1) process the SAME 16-edge tile; parity = feature half.
// Each lane still owns a contiguous float4 (16B) per (edge, spatial) row, so
// the pair's accesses cover both 64B sectors of each 128B line; regular
// (cached) loads/stores let L2 merge them. Raw s_barrier (NOT __syncthreads —
// its implicit vmcnt(0) drain would kill the load pipeline; no LDS hazard
// exists here) keeps the pair phase-aligned. acc 52 regs, b-frags 52 ->
// ~150 unified regs/wave -> ~13 waves/CU vs R5's 8 (the R5 post-mortem
// identified wave-level parallelism as the binding constraint).
__global__ __launch_bounds__(256, 3)
void leibniz_fused(const float* __restrict__ h0, const float* __restrict__ h1,
                   const float* __restrict__ h2, const float* __restrict__ g0,
                   const float* __restrict__ g1, const float* __restrict__ g2,
                   const float* __restrict__ Wg, const int* __restrict__ src,
                   float* __restrict__ out, int E)
{
  // W staged as bf16 A-fragments: [path][half][kchunk q][m] of 8 bf16 (16B),
  // entry (p,h,q,m) = W[p][m + 16h][8q..8q+7] * INV_SQRT_F
  __shared__ bf16x8 wlds[12 * 2 * 4 * 16];

  for (int c = threadIdx.x; c < 12 * 2 * 4 * 16; c += 256) {
    const int gl = c & 15;
    const int qq = (c >> 4) & 3;
    const int hf = (c >> 6) & 1;
    const int p  = c >> 7;
    const float* wp = Wg + (p * 32 + hf * 16 + gl) * 32 + qq * 8;
    bf16x8 f;
#pragma unroll
    for (int j = 0; j < 8; ++j) f[j] = (__bf16)(wp[j] * INV_SQRT_F);
    wlds[c] = f;
  }
  __syncthreads();  // real LDS hazard: full barrier required (only W loads outstanding)

  const int lane = threadIdx.x & 63;
  const int wid  = threadIdx.x >> 6;
  const int half = wid & 1;     // feature half owned by this wave
  const int tile = wid >> 1;    // edge tile within block
  const int eidx = lane & 15;   // edge within tile (B col / W-frag row index)
  const int q    = lane >> 4;   // k-chunk; D feature-row group
  int e0 = (blockIdx.x * 2 + tile) * 16;
  if (e0 > E - 16) e0 = E - 16;  // benign clamp

  const int node = src[e0 + eidx];

  const int e   = e0 + eidx;          // this lane's edge
  const int col = q * 4 + 16 * half;  // first of the lane's 4 feature columns
  const float* g0p = g0 + e * 32 + col;
  const float* g1p = g1 + (long long)e * 96 + col;
  const float* g2p = g2 + (long long)e * 288 + col;

  // ---- early-issue g0 + g1 (HBM latency overlaps the L3 h-gather below)
  f32x4 gv0 = *reinterpret_cast<const f32x4*>(g0p);
  f32x4 gv1[3];
#pragma unroll
  for (int s = 0; s < 3; ++s)
    gv1[s] = *reinterpret_cast<const f32x4*>(g1p + s * 32);

  // ---- h gather + cvt (L3-resident)
  const int k0 = q * 8;
  const bf16x8 b0 = load_frag8(h0 + node * 32 + k0);
  bf16x8 b1[3];
#pragma unroll
  for (int s = 0; s < 3; ++s) b1[s] = load_frag8(h1 + node * 96 + s * 32 + k0);
  bf16x8 b2[9];
#pragma unroll
  for (int s = 0; s < 9; ++s) b2[s] = load_frag8(h2 + node * 288 + s * 32 + k0);

  const f32x4 z4 = {0.f, 0.f, 0.f, 0.f};
  f32x4 acc0 = z4;
  f32x4 acc1[3] = {z4, z4, z4};
  f32x4 acc2[9] = {z4, z4, z4, z4, z4, z4, z4, z4, z4};

#define WFRAG(P) (wlds[(((P) * 2 + half) * 4 + q) * 16 + eidx])

  // ---- g0 phase: paths 0 (0,0->0), 3 (1,0->1), 4 (2,0->2), all 'prod'
  {
    acc0 += mfma16(WFRAG(0), b0) * gv0;
    const bf16x8 w3 = WFRAG(3);
#pragma unroll
    for (int s = 0; s < 3; ++s) acc1[s] += mfma16(w3, b1[s]) * gv0;
    const bf16x8 w4 = WFRAG(4);
#pragma unroll
    for (int s = 0; s < 9; ++s) acc2[s] += mfma16(w4, b2[s]) * gv0;
  }

  // ---- issue g2 row 0 (pipeline ahead of g1 compute)
  f32x4 gkA[3];
#pragma unroll
  for (int j = 0; j < 3; ++j)
    gkA[j] = *reinterpret_cast<const f32x4*>(g2p + j * 32);

  __builtin_amdgcn_s_barrier();  // pair alignment only; no drain, no hazard

  // ---- g1 phase: paths 1 (prod), 5 (dot), 6 (cross), 7 (outer), 8 (mat_vec)
  {
    {
      const f32x4 t = mfma16(WFRAG(1), b0);
#pragma unroll
      for (int s = 0; s < 3; ++s) acc1[s] += t * gv1[s];
    }
    {
      const bf16x8 w5 = WFRAG(5);
#pragma unroll
      for (int s = 0; s < 3; ++s) acc0 += mfma16(w5, b1[s]) * gv1[s];
    }
    {
      const bf16x8 w6 = WFRAG(6);
      const f32x4 c0 = mfma16(w6, b1[0]);
      const f32x4 c1 = mfma16(w6, b1[1]);
      const f32x4 c2 = mfma16(w6, b1[2]);
      acc1[0] += c1 * gv1[2] - c2 * gv1[1];
      acc1[1] += c2 * gv1[0] - c0 * gv1[2];
      acc1[2] += c0 * gv1[1] - c1 * gv1[0];
    }
    {
      const bf16x8 w7 = WFRAG(7);
      const f32x4 o0 = mfma16(w7, b1[0]);
      const f32x4 o1 = mfma16(w7, b1[1]);
      const f32x4 o2 = mfma16(w7, b1[2]);
      const f32x4 tr3 = (o0 * gv1[0] + o1 * gv1[1] + o2 * gv1[2]) * (1.f / 3.f);
      acc2[0] += o0 * gv1[0] - tr3;
      acc2[1] += o0 * gv1[1];
      acc2[2] += o0 * gv1[2];
      acc2[3] += o1 * gv1[0];
      acc2[4] += o1 * gv1[1] - tr3;
      acc2[5] += o1 * gv1[2];
      acc2[6] += o2 * gv1[0];
      acc2[7] += o2 * gv1[1];
      acc2[8] += o2 * gv1[2] - tr3;
    }
    {
      const bf16x8 w8 = WFRAG(8);
#pragma unroll
      for (int i = 0; i < 3; ++i)
#pragma unroll
        for (int j = 0; j < 3; ++j)
          acc1[i] += mfma16(w8, b2[i * 3 + j]) * gv1[j];
    }
  }

  // ---- issue g2 row 1
  f32x4 gkB[3];
#pragma unroll
  for (int j = 0; j < 3; ++j)
    gkB[j] = *reinterpret_cast<const f32x4*>(g2p + (3 + j) * 32);

  // ---- g2 phase: paths 2 (prod), 9 (vec_mat), 10 (double_dot), 11 (mat_mul_sym)
  f32x4 t2 = mfma16(WFRAG(2), b0);

#define G2ROW_COMPUTE(K, GK)                                                   \
  {                                                                            \
    _Pragma("unroll")                                                          \
    for (int j = 0; j < 3; ++j) acc2[(K) * 3 + j] += t2 * GK[j];               \
    {                                                                          \
      const f32x4 vk = mfma16(WFRAG(9), b1[(K)]);                              \
      _Pragma("unroll")                                                        \
      for (int j = 0; j < 3; ++j) acc1[j] += vk * GK[j];                       \
    }                                                                          \
    {                                                                          \
      const bf16x8 w10 = WFRAG(10);                                            \
      _Pragma("unroll")                                                        \
      for (int j = 0; j < 3; ++j)                                              \
        acc0 += mfma16(w10, b2[(K) * 3 + j]) * GK[j];                          \
    }                                                                          \
    {                                                                          \
      const bf16x8 w11 = WFRAG(11);                                            \
      const f32x4 m0 = mfma16(w11, b2[0 * 3 + (K)]);                           \
      const f32x4 m1 = mfma16(w11, b2[1 * 3 + (K)]);                           \
      const f32x4 m2 = mfma16(w11, b2[2 * 3 + (K)]);                           \
      const f32x4 tk3 = (m0 * GK[0] + m1 * GK[1] + m2 * GK[2]) * (1.f / 3.f);  \
      acc2[0] += m0 * GK[0] - tk3;                                             \
      acc2[4] += m1 * GK[1] - tk3;                                             \
      acc2[8] += m2 * GK[2] - tk3;                                             \
      const f32x4 s01 = (m0 * GK[1] + m1 * GK[0]) * 0.5f;                      \
      acc2[1] += s01; acc2[3] += s01;                                          \
      const f32x4 s02 = (m0 * GK[2] + m2 * GK[0]) * 0.5f;                      \
      acc2[2] += s02; acc2[6] += s02;                                          \
      const f32x4 s12 = (m1 * GK[2] + m2 * GK[1]) * 0.5f;                      \
      acc2[5] += s12; acc2[7] += s12;                                          \
    }                                                                          \
  }

  G2ROW_COMPUTE(0, gkA)

  // ---- issue g2 row 2 (reuse gkA registers)
#pragma unroll
  for (int j = 0; j < 3; ++j)
    gkA[j] = *reinterpret_cast<const f32x4*>(g2p + (6 + j) * 32);

  G2ROW_COMPUTE(1, gkB)
  G2ROW_COMPUTE(2, gkA)

#undef G2ROW_COMPUTE

  __builtin_amdgcn_s_barrier();  // align pair for the store burst

  // ---- stores: regular cached stores; pair covers both sectors of each line
  float* o0p = out + (long long)e * 32 + col;
  float* o1p = out + (long long)E * 32 + (long long)e * 96 + col;
  float* o2p = out + (long long)E * 128 + (long long)e * 288 + col;

  *reinterpret_cast<f32x4*>(o0p) = acc0;
#pragma unroll
  for (int s = 0; s < 3; ++s)
    *reinterpret_cast<f32x4*>(o1p + s * 32) = acc1[s];
#pragma unroll
  for (int s = 0; s < 9; ++s)
    *reinterpret_cast<f32x4*>(o2p + s * 32) = acc2[s];
#undef WFRAG
}

extern "C" void kernel_launch(void* const* d_in, const int* in_sizes, int n_in,
                              void* d_out, int out_size, void* d_ws, size_t ws_size,
                              hipStream_t stream) {
  const float* h0 = (const float*)d_in[0];
  const float* h1 = (const float*)d_in[1];
  const float* h2 = (const float*)d_in[2];
  const float* g0 = (const float*)d_in[3];
  const float* g1 = (const float*)d_in[4];
  const float* g2 = (const float*)d_in[5];
  const float* Wg = (const float*)d_in[6];
  const int* src = (const int*)d_in[7];  // harness passes integer inputs as int32
  const int E = in_sizes[7];
  const int blocks = (E + 31) / 32;  // 4 waves = 2 edge-tiles x 2 feature-halves
  leibniz_fused<<<blocks, 256, 0, stream>>>(h0, h1, h2, g0, g1, g2, Wg, src,
                                            (float*)d_out, E);
}

// Round 7
// 142.365 us; speedup vs baseline: 1.1846x; 1.1846x over previous
//
#include <hip/hip_runtime.h>

typedef float f32x4 __attribute__((ext_vector_type(4)));
typedef __bf16 bf16x8 __attribute__((ext_vector_type(8)));

constexpr float INV_SQRT_F = 0.17677669529663687f;  // 32^-0.5

__device__ __forceinline__ f32x4 mfma16(bf16x8 a, bf16x8 b) {
  const f32x4 z = {0.f, 0.f, 0.f, 0.f};
  return __builtin_amdgcn_mfma_f32_16x16x32_bf16(a, b, z, 0, 0, 0);
}

__device__ __forceinline__ bf16x8 cvt_frag(f32x4 u, f32x4 v) {
  bf16x8 r;
  r[0] = (__bf16)u[0]; r[1] = (__bf16)u[1]; r[2] = (__bf16)u[2]; r[3] = (__bf16)u[3];
  r[4] = (__bf16)v[0]; r[5] = (__bf16)v[1]; r[6] = (__bf16)v[2]; r[7] = (__bf16)v[3];
  return r;
}

__device__ __forceinline__ f32x4 ld4(const float* __restrict__ p) {
  return *reinterpret_cast<const f32x4*>(p);
}

// R7: R4 structure (one wave = 16 edges, BOTH feature halves; lane owns a
// contiguous feature float4 per (edge, spatial) row) + load/convert split.
// R6 post-mortem: waves are ~92% stalled on serial load round trips — each
// load_frag8 was load->wait->16 dependent cvts, so the h gather alone was
// ~13 serial L3 trips. Here ALL raw h loads (L3-resident) issue first, then
// all g0/g1 loads (HBM); vmcnt decrements in issue order, so the cvt block
// waits only on the h tail while g flies; g2 rows use a 3-buffer pipeline.
// ~2 long-latency stalls per wave instead of ~19.
__global__ __launch_bounds__(256, 2)
void leibniz_fused(const float* __restrict__ h0, const float* __restrict__ h1,
                   const float* __restrict__ h2, const float* __restrict__ g0,
                   const float* __restrict__ g1, const float* __restrict__ g2,
                   const float* __restrict__ Wg, const int* __restrict__ src,
                   float* __restrict__ out, int E)
{
  // W staged as bf16 A-fragments: [path][half][kchunk q][m] of 8 bf16 (16B),
  // entry (p,h,q,m) = W[p][m + 16h][8q..8q+7] * INV_SQRT_F
  __shared__ bf16x8 wlds[12 * 2 * 4 * 16];

  for (int c = threadIdx.x; c < 12 * 2 * 4 * 16; c += 256) {
    const int gl = c & 15;
    const int qq = (c >> 4) & 3;
    const int hf = (c >> 6) & 1;
    const int p  = c >> 7;
    const float* wp = Wg + (p * 32 + hf * 16 + gl) * 32 + qq * 8;
    bf16x8 f;
#pragma unroll
    for (int j = 0; j < 8; ++j) f[j] = (__bf16)(wp[j] * INV_SQRT_F);
    wlds[c] = f;
  }
  __syncthreads();

  const int lane = threadIdx.x & 63;
  const int wid  = threadIdx.x >> 6;
  const int eidx = lane & 15;   // edge within tile (B col / W-frag row index)
  const int q    = lane >> 4;   // k-chunk; D feature-row group
  int e0 = (blockIdx.x * 4 + wid) * 16;
  if (e0 > E - 16) e0 = E - 16;  // benign clamp

  const int node = src[e0 + eidx];
  const int k0 = q * 8;

  const int e   = e0 + eidx;   // this lane's edge
  const int col = q * 4;       // first of the lane's 4 feature columns (half 0)
  const float* g0p = g0 + e * 32 + col;
  const float* g1p = g1 + (long long)e * 96 + col;
  const float* g2p = g2 + (long long)e * 288 + col;

  // ---- batch-issue ALL raw h loads (L3-resident; issued first so vmcnt
  //      order lets the cvt block proceed while g loads are still in flight)
  const float* h0p = h0 + node * 32 + k0;
  const float* h1p = h1 + node * 96 + k0;
  const float* h2p = h2 + (long long)node * 288 + k0;
  f32x4 r0a = ld4(h0p);
  f32x4 r0b = ld4(h0p + 4);
  f32x4 r1[6];
#pragma unroll
  for (int s = 0; s < 3; ++s) {
    r1[2 * s]     = ld4(h1p + s * 32);
    r1[2 * s + 1] = ld4(h1p + s * 32 + 4);
  }
  f32x4 r2[18];
#pragma unroll
  for (int s = 0; s < 9; ++s) {
    r2[2 * s]     = ld4(h2p + s * 32);
    r2[2 * s + 1] = ld4(h2p + s * 32 + 4);
  }

  // ---- then g0 + g1 (HBM; longest latency, overlapped by cvt + g0 compute)
  f32x4 gv0[2];
  gv0[0] = ld4(g0p);
  gv0[1] = ld4(g0p + 16);
  f32x4 gv1[3][2];
#pragma unroll
  for (int s = 0; s < 3; ++s) {
    gv1[s][0] = ld4(g1p + s * 32);
    gv1[s][1] = ld4(g1p + s * 32 + 16);
  }

  // ---- convert h -> bf16 fragments (waits only on the h load tail)
  const bf16x8 b0 = cvt_frag(r0a, r0b);
  bf16x8 b1[3];
#pragma unroll
  for (int s = 0; s < 3; ++s) b1[s] = cvt_frag(r1[2 * s], r1[2 * s + 1]);
  bf16x8 b2[9];
#pragma unroll
  for (int s = 0; s < 9; ++s) b2[s] = cvt_frag(r2[2 * s], r2[2 * s + 1]);

  // ---- issue g2 rows 0 and 1 (pipeline ahead of g0/g1 compute)
  f32x4 gkA[3][2], gkB[3][2];
#pragma unroll
  for (int j = 0; j < 3; ++j) {
    gkA[j][0] = ld4(g2p + j * 32);
    gkA[j][1] = ld4(g2p + j * 32 + 16);
  }
#pragma unroll
  for (int j = 0; j < 3; ++j) {
    gkB[j][0] = ld4(g2p + (3 + j) * 32);
    gkB[j][1] = ld4(g2p + (3 + j) * 32 + 16);
  }

  const f32x4 z4 = {0.f, 0.f, 0.f, 0.f};
  f32x4 acc0[2] = {z4, z4};
  f32x4 acc1[3][2];
  f32x4 acc2[9][2];
#pragma unroll
  for (int s = 0; s < 3; ++s) { acc1[s][0] = z4; acc1[s][1] = z4; }
#pragma unroll
  for (int s = 0; s < 9; ++s) { acc2[s][0] = z4; acc2[s][1] = z4; }

#define WFRAG(P, H) (wlds[(((P) * 2 + (H)) * 4 + q) * 16 + eidx])

  // ---- g0 phase: paths 0 (0,0->0), 3 (1,0->1), 4 (2,0->2), all 'prod'
#pragma unroll
  for (int h = 0; h < 2; ++h) {
    acc0[h] += mfma16(WFRAG(0, h), b0) * gv0[h];
    const bf16x8 w3 = WFRAG(3, h);
#pragma unroll
    for (int s = 0; s < 3; ++s) acc1[s][h] += mfma16(w3, b1[s]) * gv0[h];
    const bf16x8 w4 = WFRAG(4, h);
#pragma unroll
    for (int s = 0; s < 9; ++s) acc2[s][h] += mfma16(w4, b2[s]) * gv0[h];
  }

  // ---- g1 phase: paths 1 (prod), 5 (dot), 6 (cross), 7 (outer), 8 (mat_vec)
#pragma unroll
  for (int h = 0; h < 2; ++h) {
    {
      const f32x4 t = mfma16(WFRAG(1, h), b0);
#pragma unroll
      for (int s = 0; s < 3; ++s) acc1[s][h] += t * gv1[s][h];
    }
    {
      const bf16x8 w5 = WFRAG(5, h);
#pragma unroll
      for (int s = 0; s < 3; ++s) acc0[h] += mfma16(w5, b1[s]) * gv1[s][h];
    }
    {
      const bf16x8 w6 = WFRAG(6, h);
      const f32x4 c0 = mfma16(w6, b1[0]);
      const f32x4 c1 = mfma16(w6, b1[1]);
      const f32x4 c2 = mfma16(w6, b1[2]);
      acc1[0][h] += c1 * gv1[2][h] - c2 * gv1[1][h];
      acc1[1][h] += c2 * gv1[0][h] - c0 * gv1[2][h];
      acc1[2][h] += c0 * gv1[1][h] - c1 * gv1[0][h];
    }
    {
      const bf16x8 w7 = WFRAG(7, h);
      const f32x4 o0 = mfma16(w7, b1[0]);
      const f32x4 o1 = mfma16(w7, b1[1]);
      const f32x4 o2 = mfma16(w7, b1[2]);
      const f32x4 tr3 = (o0 * gv1[0][h] + o1 * gv1[1][h] + o2 * gv1[2][h]) * (1.f / 3.f);
      acc2[0][h] += o0 * gv1[0][h] - tr3;
      acc2[1][h] += o0 * gv1[1][h];
      acc2[2][h] += o0 * gv1[2][h];
      acc2[3][h] += o1 * gv1[0][h];
      acc2[4][h] += o1 * gv1[1][h] - tr3;
      acc2[5][h] += o1 * gv1[2][h];
      acc2[6][h] += o2 * gv1[0][h];
      acc2[7][h] += o2 * gv1[1][h];
      acc2[8][h] += o2 * gv1[2][h] - tr3;
    }
    {
      const bf16x8 w8 = WFRAG(8, h);
#pragma unroll
      for (int i = 0; i < 3; ++i)
#pragma unroll
        for (int j = 0; j < 3; ++j)
          acc1[i][h] += mfma16(w8, b2[i * 3 + j]) * gv1[j][h];
    }
  }

  // ---- issue g2 row 2 (3rd buffer; issued before any g2-row compute)
  f32x4 gkC[3][2];
#pragma unroll
  for (int j = 0; j < 3; ++j) {
    gkC[j][0] = ld4(g2p + (6 + j) * 32);
    gkC[j][1] = ld4(g2p + (6 + j) * 32 + 16);
  }

  // ---- g2 phase: paths 2 (prod), 9 (vec_mat), 10 (double_dot), 11 (mat_mul_sym)
  f32x4 t2[2];
  t2[0] = mfma16(WFRAG(2, 0), b0);
  t2[1] = mfma16(WFRAG(2, 1), b0);

#define G2ROW_COMPUTE(K, GK)                                                   \
  {                                                                            \
    _Pragma("unroll")                                                          \
    for (int h = 0; h < 2; ++h) {                                              \
      _Pragma("unroll")                                                        \
      for (int j = 0; j < 3; ++j) acc2[(K) * 3 + j][h] += t2[h] * GK[j][h];    \
      {                                                                        \
        const f32x4 vk = mfma16(WFRAG(9, h), b1[(K)]);                         \
        _Pragma("unroll")                                                      \
        for (int j = 0; j < 3; ++j) acc1[j][h] += vk * GK[j][h];               \
      }                                                                        \
      {                                                                        \
        const bf16x8 w10 = WFRAG(10, h);                                       \
        _Pragma("unroll")                                                      \
        for (int j = 0; j < 3; ++j)                                            \
          acc0[h] += mfma16(w10, b2[(K) * 3 + j]) * GK[j][h];                  \
      }                                                                        \
      {                                                                        \
        const bf16x8 w11 = WFRAG(11, h);                                       \
        const f32x4 m0 = mfma16(w11, b2[0 * 3 + (K)]);                         \
        const f32x4 m1 = mfma16(w11, b2[1 * 3 + (K)]);                         \
        const f32x4 m2 = mfma16(w11, b2[2 * 3 + (K)]);                         \
        const f32x4 tk3 =                                                      \
            (m0 * GK[0][h] + m1 * GK[1][h] + m2 * GK[2][h]) * (1.f / 3.f);     \
        acc2[0][h] += m0 * GK[0][h] - tk3;                                     \
        acc2[4][h] += m1 * GK[1][h] - tk3;                                     \
        acc2[8][h] += m2 * GK[2][h] - tk3;                                     \
        const f32x4 s01 = (m0 * GK[1][h] + m1 * GK[0][h]) * 0.5f;              \
        acc2[1][h] += s01; acc2[3][h] += s01;                                  \
        const f32x4 s02 = (m0 * GK[2][h] + m2 * GK[0][h]) * 0.5f;              \
        acc2[2][h] += s02; acc2[6][h] += s02;                                  \
        const f32x4 s12 = (m1 * GK[2][h] + m2 * GK[1][h]) * 0.5f;              \
        acc2[5][h] += s12; acc2[7][h] += s12;                                  \
      }                                                                        \
    }                                                                          \
  }

  G2ROW_COMPUTE(0, gkA)
  G2ROW_COMPUTE(1, gkB)
  G2ROW_COMPUTE(2, gkC)

#undef G2ROW_COMPUTE

  // ---- stores: regular cached float4 pairs; wave covers full 128B lines
  float* o0p = out + (long long)e * 32 + col;
  float* o1p = out + (long long)E * 32 + (long long)e * 96 + col;
  float* o2p = out + (long long)E * 128 + (long long)e * 288 + col;

  *reinterpret_cast<f32x4*>(o0p)      = acc0[0];
  *reinterpret_cast<f32x4*>(o0p + 16) = acc0[1];
#pragma unroll
  for (int s = 0; s < 3; ++s) {
    *reinterpret_cast<f32x4*>(o1p + s * 32)      = acc1[s][0];
    *reinterpret_cast<f32x4*>(o1p + s * 32 + 16) = acc1[s][1];
  }
#pragma unroll
  for (int s = 0; s < 9; ++s) {
    *reinterpret_cast<f32x4*>(o2p + s * 32)      = acc2[s][0];
    *reinterpret_cast<f32x4*>(o2p + s * 32 + 16) = acc2[s][1];
  }
#undef WFRAG
}

extern "C" void kernel_launch(void* const* d_in, const int* in_sizes, int n_in,
                              void* d_out, int out_size, void* d_ws, size_t ws_size,
                              hipStream_t stream) {
  const float* h0 = (const float*)d_in[0];
  const float* h1 = (const float*)d_in[1];
  const float* h2 = (const float*)d_in[2];
  const float* g0 = (const float*)d_in[3];
  const float* g1 = (const float*)d_in[4];
  const float* g2 = (const float*)d_in[5];
  const float* Wg = (const float*)d_in[6];
  const int* src = (const int*)d_in[7];  // harness passes integer inputs as int32
  const int E = in_sizes[7];
  const int blocks = (E + 63) / 64;  // 4 waves x 16 edges
  leibniz_fused<<<blocks, 256, 0, stream>>>(h0, h1, h2, g0, g1, g2, Wg, src,
                                            (float*)d_out, E);
}